// Round 6
// baseline (10677.512 us; speedup 1.0000x reference)
//
#include <hip/hip_runtime.h>

typedef unsigned short u16;
typedef unsigned int u32;
typedef unsigned long long u64;
typedef __attribute__((ext_vector_type(4))) float f32x4;
typedef __attribute__((ext_vector_type(8))) short bf16x8;
typedef __attribute__((ext_vector_type(4))) u32 u32x4;   // asm-friendly 128-bit

#define S_LEN 2048
#define BATCH 32
#define HID 512
#define NG 2048           // 4*HID
#define NWG 64            // recurrence workgroups (merged: each does L1+L2 slice)
#define SLICE 8           // hidden units per WG per layer (HID/NWG)

// Sentinel dword: two bf16 2.0 halves. |h| = |sigmoid*tanh| < 1 strictly, so
// no published h dword can ever equal this pattern.
#define SENT 0x40004000u

#define MFMA16(a, b, c) __builtin_amdgcn_mfma_f32_16x16x32_bf16((a), (b), (c), 0, 0, 0)

__device__ __forceinline__ u16 f2bf(float f) {
  u32 u = __builtin_bit_cast(u32, f);
  u32 r = (u + 0x7FFFu + ((u >> 16) & 1u)) >> 16;   // RNE
  return (u16)r;
}
__device__ __forceinline__ float bf2f(u16 u) {
  u32 x = ((u32)u) << 16;
  return __builtin_bit_cast(float, x);
}
__device__ __forceinline__ float sigf(float x) {
  return 1.0f / (1.0f + __expf(-x));
}
__device__ __forceinline__ float tanh_fast(float x) {
  float a = fabsf(x);
  float t = __expf(-2.0f * a);
  float r = (1.0f - t) / (1.0f + t);
  return x < 0.0f ? -r : r;
}

// 16B cache-bypass load/store (sc0 sc1): read/write the cross-XCD coherence
// point directly. vmcnt for these is NOT compiler-tracked — use bypass_wait()
// before consuming results. Operands are ext_vector_type (clang can't pass
// struct-typed uint4 as asm INPUT; ext vectors lower to VGPR quads).
__device__ __forceinline__ u32x4 bypass_ld16(const u16* p) {
  u32x4 r;
  asm volatile("global_load_dwordx4 %0, %1, off sc0 sc1"
               : "=v"(r) : "v"(p) : "memory");
  return r;
}
__device__ __forceinline__ void bypass_st16(u16* p, u32x4 v) {
  asm volatile("global_store_dwordx4 %0, %1, off sc0 sc1"
               :: "v"(p), "v"(v) : "memory");
}
__device__ __forceinline__ void bypass_wait() {
  asm volatile("s_waitcnt vmcnt(0)" ::: "memory");
  __builtin_amdgcn_sched_barrier(0);
}

// ---------------------------------------------------------------------------
// Sentinel fill for hb1+hb2 (contiguous 128 MiB). Bypass stores only: a
// cached fill would leave dirty sentinel lines in L2s that could evict later
// and clobber published h values at the coherence point.
// ---------------------------------------------------------------------------
__global__ void fill_sentinel(u16* base, int n16) {
  u32x4 v = {SENT, SENT, SENT, SENT};
  const int step = gridDim.x * 256;
  for (int i = blockIdx.x * 256 + threadIdx.x; i < n16; i += step)
    bypass_st16(base + (size_t)i * 8, v);
  asm volatile("s_waitcnt vmcnt(0)" ::: "memory");
}

// ---------------------------------------------------------------------------
// Weight prep: fp32 -> bf16 copies of W_ih / W_hh, bias sum.
// ---------------------------------------------------------------------------
__global__ void prep_weights(const float* __restrict__ Wih, const float* __restrict__ Whh,
                             const float* __restrict__ bih, const float* __restrict__ bhh,
                             u16* __restrict__ wih_bf, u16* __restrict__ whh_bf,
                             float* __restrict__ bsum) {
  const int i = blockIdx.x * 256 + threadIdx.x;   // grid covers exactly 2*NG*HID
  wih_bf[i] = f2bf(Wih[i]);
  whh_bf[i] = f2bf(Whh[i]);
  if (i < 2 * NG) bsum[i] = bih[i] + bhh[i];
}

// ---------------------------------------------------------------------------
// GEMM (layer-1 input contribution only):
//   xg[r][n] = sum_k X[b][t][k] * Wih1[n][k] + bias[n],  r = t*32+b
// 64x64 tiles, BK=64, 256 threads (4 waves, 2x2 quadrants of 32x32 each).
// ---------------------------------------------------------------------------
__global__ __launch_bounds__(256)
void gemm_xg(const float* __restrict__ Ap, const u16* __restrict__ Bw,
             const float* __restrict__ bias, void* __restrict__ xgp, int xg32)
{
  __shared__ __align__(16) u16 aT[64][72];
  __shared__ __align__(16) u16 bT[64][72];
  const int tid = threadIdx.x;
  const int nb = blockIdx.x;     // 0..31 (N tiles)
  const int mb = blockIdx.y;     // 0..1023 (M tiles)
  const int lane = tid & 63, wid = tid >> 6;
  const int mw = (wid & 1) * 32, nw = (wid >> 1) * 32;
  f32x4 acc[2][2] = {{{0.f,0.f,0.f,0.f},{0.f,0.f,0.f,0.f}},
                     {{0.f,0.f,0.f,0.f},{0.f,0.f,0.f,0.f}}};

  const int arow = tid >> 2;
  const int gm = mb * 64 + arow;
  const int t = gm >> 5, b = gm & 31;
  const size_t aoff = ((size_t)b * S_LEN + t) * HID;
  const size_t boff = (size_t)(nb * 64 + arow) * HID;
  const int c16 = (tid & 3) * 16;

  for (int kb = 0; kb < 8; ++kb) {
    const int k0 = kb * 64;
    {
      const float* src = Ap + aoff + k0 + c16;
      #pragma unroll
      for (int q = 0; q < 4; ++q) {
        const float4 v = ((const float4*)src)[q];
        ushort4 w4;
        w4.x = f2bf(v.x); w4.y = f2bf(v.y); w4.z = f2bf(v.z); w4.w = f2bf(v.w);
        *(ushort4*)&aT[arow][c16 + q * 4] = w4;
      }
    }
    {
      const uint4* src = (const uint4*)(Bw + boff + k0 + c16);
      const uint4 v0 = src[0], v1 = src[1];
      *(uint4*)&bT[arow][c16] = v0;
      *(uint4*)&bT[arow][c16 + 8] = v1;
    }
    __syncthreads();
    #pragma unroll
    for (int kk = 0; kk < 2; ++kk) {
      const int ko = kk * 32 + (lane >> 4) * 8;
      const bf16x8 a0 = *(const bf16x8*)&aT[mw +      (lane & 15)][ko];
      const bf16x8 a1 = *(const bf16x8*)&aT[mw + 16 + (lane & 15)][ko];
      const bf16x8 b0 = *(const bf16x8*)&bT[nw +      (lane & 15)][ko];
      const bf16x8 b1 = *(const bf16x8*)&bT[nw + 16 + (lane & 15)][ko];
      acc[0][0] = MFMA16(a0, b0, acc[0][0]);
      acc[0][1] = MFMA16(a0, b1, acc[0][1]);
      acc[1][0] = MFMA16(a1, b0, acc[1][0]);
      acc[1][1] = MFMA16(a1, b1, acc[1][1]);
    }
    __syncthreads();
  }
  const int col = lane & 15, rb = (lane >> 4) * 4;
  #pragma unroll
  for (int fm = 0; fm < 2; ++fm) {
    #pragma unroll
    for (int fn = 0; fn < 2; ++fn) {
      const int gn = nb * 64 + nw + fn * 16 + col;
      const float bv = bias[gn];
      #pragma unroll
      for (int r = 0; r < 4; ++r) {
        const size_t gmr = (size_t)(mb * 64 + mw + fm * 16 + rb + r);
        const float v = acc[fm][fn][r] + bv;
        if (xg32) ((float*)xgp)[gmr * NG + gn] = v;
        else      ((u16*)xgp)[gmr * NG + gn] = f2bf(v);
      }
    }
  }
}

// ---------------------------------------------------------------------------
// MERGED 2-layer LSTM recurrence. 64 persistent WGs; WG w owns hidden slice
// [w*8, w*8+8) of BOTH layers. At iteration t it computes:
//   L1 step t   : needs h1[t-1] (rec) + precomputed xg1[t]
//   L2 step t-1 : needs h1[t-1] (input!) + h2[t-2] (rec)
// Both consume the SAME h1[t-1] tile -> one 32KB read serves two passes.
// Broadcast volume drops 6MB -> 4MB/step (the measured limiter), and the
// two per-step rendezvous collapse into one.
//
// Weights live in REGISTERS: 3 matrices x 16 bf16x8 fragments = 192 VGPR/lane
// (1 wave/SIMD config -> 512-reg budget). No weight LDS, no weight ds_reads.
//
// DATA-IS-THE-FLAG handoff (round-5, verified): hb pre-filled with SENT;
// producers fire-and-forget bypass dword stores; consumer waves poll their
// quarter of the tiles with 16B bypass loads until no dword equals SENT.
// Dependencies are strictly iteration t-1 -> t: no deadlock.
// ---------------------------------------------------------------------------
__global__ __launch_bounds__(256, 1)
void lstm_fused(const void* __restrict__ xgp, int xg32,
                const u16* __restrict__ whh_bf, const u16* __restrict__ wih_bf,
                const float* __restrict__ bsum,
                u16* __restrict__ hb1, u16* __restrict__ hb2,
                float* __restrict__ dout)
{
  __shared__ __align__(16) u16 hA[32][520];   // h1[t-1] (batch x HID)
  __shared__ __align__(16) u16 hB[32][520];   // h2[t-2]
  __shared__ float gT1[32][33];               // L1 gate tile (batch x 32 cols)
  __shared__ float gT2[32][33];               // L2 gate tile

  const int w = blockIdx.x;      // 0..63
  const int tid = threadIdx.x;
  const int lane = tid & 63, wid = tid >> 6;
  const int mw = (wid & 1) * 16, nw = (wid >> 1) * 16;
  const int b = tid >> 3, j = tid & 7;

  // ---- weight fragments -> registers (192 VGPR/lane) ----
  // local gate row lrow in [0,32): global gate row = (lrow>>3)*HID + w*8 + (lrow&7)
  bf16x8 w1f[16], wIf[16], w2f[16];
  {
    const int lrow = nw + (lane & 15);
    const size_t gnrow = (size_t)(lrow >> 3) * HID + w * SLICE + (lrow & 7);
    const u16* W1 = whh_bf + gnrow * HID;                        // Whh layer 1
    const u16* WI = wih_bf + (size_t)NG * HID + gnrow * HID;     // Wih layer 2
    const u16* W2 = whh_bf + (size_t)NG * HID + gnrow * HID;     // Whh layer 2
    #pragma unroll
    for (int kt = 0; kt < 16; ++kt) {
      const int ko = kt * 32 + (lane >> 4) * 8;
      w1f[kt] = *(const bf16x8*)&W1[ko];
      wIf[kt] = *(const bf16x8*)&WI[ko];
      w2f[kt] = *(const bf16x8*)&W2[ko];
    }
  }
  float bv[4];
  #pragma unroll
  for (int g = 0; g < 4; ++g) bv[g] = bsum[NG + g * HID + w * SLICE + j];

  float c1 = 0.0f, c2 = 0.0f;
  __syncthreads();

  // S_LEN+1 iterations: t in [0,S_LEN]; L1 active for t<S_LEN, L2 computes
  // step u=t-1 for t>=1.
  for (int t = 0; t <= S_LEN; ++t) {
    const int u = t - 1;
    float xv[4] = {0.f, 0.f, 0.f, 0.f};

    if (t < S_LEN) {
      // prefetch xg1[t]; loads in flight across the poll. Non-temporal: xg
      // is streamed once, keep it out of L2/L3 (h lives there).
      if (xg32) {
        const float* x = (const float*)xgp + ((size_t)t * BATCH + b) * NG + w * SLICE + j;
        #pragma unroll
        for (int g = 0; g < 4; ++g) xv[g] = __builtin_nontemporal_load(&x[g * HID]);
      } else {
        const u16* x = (const u16*)xgp + ((size_t)t * BATCH + b) * NG + w * SLICE + j;
        #pragma unroll
        for (int g = 0; g < 4; ++g) xv[g] = bf2f(__builtin_nontemporal_load(&x[g * HID]));
      }
    }

    // ---- poll-load h tiles (data is the flag) ----
    if (t >= 1) {
      const u16* srcA = hb1 + (size_t)(t - 1) * (BATCH * HID);
      const u16* srcB = (t >= 2) ? hb2 + (size_t)(t - 2) * (BATCH * HID) : nullptr;
      u32x4 vA[8], vB[8];
      while (true) {
        #pragma unroll
        for (int ii = 0; ii < 8; ++ii) {
          const int i = tid + ii * 256, r = i >> 6, cc = i & 63;
          vA[ii] = bypass_ld16(srcA + (size_t)r * HID + cc * 8);
        }
        if (srcB) {
          #pragma unroll
          for (int ii = 0; ii < 8; ++ii) {
            const int i = tid + ii * 256, r = i >> 6, cc = i & 63;
            vB[ii] = bypass_ld16(srcB + (size_t)r * HID + cc * 8);
          }
        }
        bypass_wait();   // drain untracked asm loads before checking
        u32 bad = 0;
        #pragma unroll
        for (int ii = 0; ii < 8; ++ii)
          bad |= (u32)(vA[ii][0] == SENT) | (u32)(vA[ii][1] == SENT) |
                 (u32)(vA[ii][2] == SENT) | (u32)(vA[ii][3] == SENT);
        if (srcB) {
          #pragma unroll
          for (int ii = 0; ii < 8; ++ii)
            bad |= (u32)(vB[ii][0] == SENT) | (u32)(vB[ii][1] == SENT) |
                   (u32)(vB[ii][2] == SENT) | (u32)(vB[ii][3] == SENT);
        }
        if (__all((int)(bad == 0))) break;   // wave's quarter fully published
      }
      #pragma unroll
      for (int ii = 0; ii < 8; ++ii) {
        const int i = tid + ii * 256, r = i >> 6, cc = i & 63;
        *(u32x4*)&hA[r][cc * 8] = vA[ii];
      }
      if (srcB) {
        #pragma unroll
        for (int ii = 0; ii < 8; ++ii) {
          const int i = tid + ii * 256, r = i >> 6, cc = i & 63;
          *(u32x4*)&hB[r][cc * 8] = vB[ii];
        }
      }
    }
    __syncthreads();   // barrier #1: all waves' quarters valid + in LDS

    // ---- MFMA: 48 matmuls max, weights from registers ----
    f32x4 ac1a = {0.f,0.f,0.f,0.f}, ac1b = {0.f,0.f,0.f,0.f};
    f32x4 ac2a = {0.f,0.f,0.f,0.f}, ac2b = {0.f,0.f,0.f,0.f};
    if (t >= 1) {
      bf16x8 af[16];   // hA fragments: shared by L1-rec and L2-in passes
      #pragma unroll
      for (int kt = 0; kt < 16; ++kt) {
        const int ko = kt * 32 + (lane >> 4) * 8;
        af[kt] = *(const bf16x8*)&hA[mw + (lane & 15)][ko];
      }
      if (t < S_LEN) {     // L1 recurrent: h1[t-1] @ Whh1^T
        #pragma unroll
        for (int kt = 0; kt < 16; ++kt) {
          if (kt & 1) ac1b = MFMA16(af[kt], w1f[kt], ac1b);
          else        ac1a = MFMA16(af[kt], w1f[kt], ac1a);
        }
      }
      #pragma unroll
      for (int kt = 0; kt < 16; ++kt)      // L2 input: h1[t-1] @ Wih2^T
        ac2a = MFMA16(af[kt], wIf[kt], ac2a);
      if (t >= 2) {        // L2 recurrent: h2[t-2] @ Whh2^T
        #pragma unroll
        for (int kt = 0; kt < 16; ++kt) {
          const int ko = kt * 32 + (lane >> 4) * 8;
          const bf16x8 bfr = *(const bf16x8*)&hB[mw + (lane & 15)][ko];
          ac2b = MFMA16(bfr, w2f[kt], ac2b);
        }
      }
    }
    const f32x4 acc1 = ac1a + ac1b;
    const f32x4 acc2 = ac2a + ac2b;

    // gate tiles -> LDS
    #pragma unroll
    for (int r = 0; r < 4; ++r) {
      gT1[mw + (lane >> 4) * 4 + r][nw + (lane & 15)] = acc1[r];
      gT2[mw + (lane >> 4) * 4 + r][nw + (lane & 15)] = acc2[r];
    }
    __syncthreads();   // barrier #2: gT ready; all waves done with hA/hB

    // ---- L1 gates: produce + publish h1[t] (publish FIRST: it gates the
    //      whole chip's next step) ----
    if (t < S_LEN) {
      float pre[4];
      #pragma unroll
      for (int g = 0; g < 4; ++g) pre[g] = xv[g] + gT1[b][g * SLICE + j];
      const float gi = sigf(pre[0]);
      const float gf = sigf(pre[1]);
      const float gg = tanh_fast(pre[2]);
      const float go = sigf(pre[3]);
      c1 = gf * c1 + gi * gg;
      const float h = go * tanh_fast(c1);
      const u32 me  = (u32)f2bf(h);
      const u32 oth = (u32)__shfl_xor((int)me, 1);
      if ((j & 1) == 0) {
        u32* dst = (u32*)(hb1 + (size_t)t * (BATCH * HID) + b * HID + w * SLICE + j);
        asm volatile("global_store_dword %0, %1, off sc0 sc1"
                     :: "v"(dst), "v"(me | (oth << 16)) : "memory");
      }
    }

    // ---- L2 gates: produce + publish h2[u], write dout ----
    if (t >= 1) {
      float pre[4];
      #pragma unroll
      for (int g = 0; g < 4; ++g) pre[g] = bv[g] + gT2[b][g * SLICE + j];
      const float gi = sigf(pre[0]);
      const float gf = sigf(pre[1]);
      const float gg = tanh_fast(pre[2]);
      const float go = sigf(pre[3]);
      c2 = gf * c2 + gi * gg;
      const float h = go * tanh_fast(c2);
      const u32 me  = (u32)f2bf(h);
      const u32 oth = (u32)__shfl_xor((int)me, 1);
      if ((j & 1) == 0) {
        u32* dst = (u32*)(hb2 + (size_t)u * (BATCH * HID) + b * HID + w * SLICE + j);
        asm volatile("global_store_dword %0, %1, off sc0 sc1"
                     :: "v"(dst), "v"(me | (oth << 16)) : "memory");
      }
      // dout: plain cached stores, off the critical path (drain lazily)
      dout[((size_t)b * S_LEN + u) * HID + w * SLICE + j] = h;
      if (u == S_LEN - 1) {
        dout[(size_t)BATCH * S_LEN * HID + b * HID + w * SLICE + j] = h;
        dout[(size_t)BATCH * S_LEN * HID + (size_t)BATCH * HID + b * HID + w * SLICE + j] = c2;
      }
    }
  }
}

// ---------------------------------------------------------------------------
extern "C" void kernel_launch(void* const* d_in, const int* in_sizes, int n_in,
                              void* d_out, int out_size, void* d_ws, size_t ws_size,
                              hipStream_t stream) {
  (void)in_sizes; (void)n_in; (void)out_size;
  const float* X   = (const float*)d_in[0];
  const float* Wih = (const float*)d_in[1];
  const float* Whh = (const float*)d_in[2];
  const float* bih = (const float*)d_in[3];
  const float* bhh = (const float*)d_in[4];

  const size_t M      = (size_t)S_LEN * BATCH;   // 65536
  const size_t xg_b32 = M * NG * 4;              // 512 MiB
  const size_t xg_b16 = M * NG * 2;
  const size_t hb_b   = M * HID * 2;             // 64 MiB
  const size_t w_b    = 2ull * NG * HID * 2;     // 4 MiB (both layers)
  const size_t fixed  = 2 * hb_b + 2 * w_b + 16384 + 1024;

  const int xg32 = (ws_size >= xg_b32 + fixed) ? 1 : 0;

  char* p = (char*)d_ws;
  auto carve = [&](size_t bytes) { char* q = p; p += (bytes + 255) & ~(size_t)255; return q; };
  void* xg     = carve(xg32 ? xg_b32 : xg_b16);
  u16*  hb1    = (u16*)carve(hb_b);
  u16*  hb2    = (u16*)carve(hb_b);   // contiguous with hb1
  u16*  wih_bf = (u16*)carve(w_b);
  u16*  whh_bf = (u16*)carve(w_b);
  float* bsum  = (float*)carve(16384);

  // sentinel-fill hb1+hb2 (contiguous 128 MiB) every launch: bench-iteration
  // reuse must never satisfy the data-poll with stale state.
  fill_sentinel<<<2048, 256, 0, stream>>>(hb1, (int)((2 * hb_b) / 16));
  prep_weights<<<(2 * NG * HID) / 256, 256, 0, stream>>>(Wih, Whh, bih, bhh,
                                                         wih_bf, whh_bf, bsum);
  gemm_xg<<<dim3(32, 1024), 256, 0, stream>>>(X, wih_bf, bsum, xg, xg32);
  lstm_fused<<<NWG, 256, 0, stream>>>(xg, xg32, whh_bf, wih_bf, bsum,
                                      hb1, hb2, (float*)d_out);
}